// Round 5
// baseline (186.236 us; speedup 1.0000x reference)
//
#include <hip/hip_runtime.h>
#include <hip/hip_bf16.h>

#define NSPLIT 8
#define BIGF 1e30f
#define MARGIN 0.3f
#define DK 128
#define LDA 136   // padded LDS stride (bf16 elems)

typedef __attribute__((ext_vector_type(8))) short bf16x8;
typedef __attribute__((ext_vector_type(4))) float f32x4;

// workspace word offsets
#define WS_HP   0                  // 8192 u32 keys: max d2_pos (order-preserving map)
#define WS_HN   8192               // 8192 u32 keys: ~key(d2_neg) => min via complement
#define WS_BCNT 16384              // u32 completion counter
#define WS_SQ   16388              // 8192 f32 squared norms
#define WS_XB   24580              // bf16 X copy (byte off 98320, 16B aligned)

// Order-preserving float->uint key: works for negative values too, so the
// -BIGF / +BIGF sentinels survive the atomic merge and encode validity.
// Init 0 is the identity for atomicMax (all real keys > 0).
__device__ __forceinline__ unsigned encf(float f) {
    unsigned u = __float_as_uint(f);
    return (u & 0x80000000u) ? ~u : (u | 0x80000000u);
}
__device__ __forceinline__ float decf(unsigned k) {
    return (k & 0x80000000u) ? __uint_as_float(k & 0x7FFFFFFFu)
                             : __uint_as_float(~k);
}

// Kernel 1: bf16 copy of X + exact fp32 squared norms + zero-init of ws
// (harness re-poisons ws to 0xAA before every call).
__global__ void prep_kernel(const float* __restrict__ x, ushort* __restrict__ xb,
                            float* __restrict__ sq, unsigned* __restrict__ hp,
                            unsigned* __restrict__ hn, unsigned* __restrict__ bcnt,
                            int N) {
    if (blockIdx.x == 0 && threadIdx.x == 0) *bcnt = 0u;
    int wave = threadIdx.x >> 6;
    int lane = threadIdx.x & 63;
    int row = blockIdx.x * 4 + wave;
    if (row >= N) return;
    const float2* xr = (const float2*)(x + (size_t)row * DK);
    float2 v = xr[lane];
    __hip_bfloat16 b0 = __float2bfloat16(v.x);
    __hip_bfloat16 b1 = __float2bfloat16(v.y);
    ushort2 st;
    st.x = *(ushort*)&b0;
    st.y = *(ushort*)&b1;
    ((ushort2*)(xb + (size_t)row * DK))[lane] = st;
    float s = v.x * v.x + v.y * v.y;
    #pragma unroll
    for (int o = 32; o > 0; o >>= 1) s += __shfl_xor(s, o, 64);
    if (lane == 0) {
        sq[row] = s;
        hp[row] = 0u;
        hn[row] = 0u;
    }
}

// Kernel 2: fused bf16-MFMA dist^2 + masked max/min, register-pipelined B,
// atomic key merge, and finalize folded into the last block.
// Grid (N/128, NSPLIT); 4 waves per block, each owns a 64x64 quadrant.
__global__ __launch_bounds__(256, 2) void tile_kernel(
    const ushort* __restrict__ xb, const float* __restrict__ sq,
    const int* __restrict__ lab,
    unsigned* __restrict__ hp_bits, unsigned* __restrict__ hn_bits,
    unsigned* __restrict__ bcnt, float* __restrict__ out, int N)
{
    __shared__ ushort a_s[128 * LDA];
    __shared__ int   laba_s[128];
    __shared__ float red_hp[128][2];
    __shared__ float red_hn[128][2];
    __shared__ float s_sum[256];
    __shared__ float s_cnt[256];
    __shared__ bool  s_last;

    const int tid  = threadIdx.x;
    const int lane = tid & 63;
    const int wave = tid >> 6;
    const int m16  = lane & 15;
    const int quad = lane >> 4;
    const int rbase = blockIdx.x * 128;
    const int wrow = (wave >> 1) * 64;
    const int wcol = (wave & 1) * 64;

    for (int c = tid; c < 128 * 16; c += 256) {
        int r = c >> 4, c8 = c & 15;
        *(bf16x8*)(a_s + r * LDA + c8 * 8) =
            *(const bf16x8*)(xb + (size_t)(rbase + r) * DK + c8 * 8);
    }
    if (tid < 128) laba_s[tid] = lab[rbase + tid];
    __syncthreads();

    int rlab[4][4];
    #pragma unroll
    for (int mt = 0; mt < 4; ++mt)
        #pragma unroll
        for (int r = 0; r < 4; ++r)
            rlab[mt][r] = laba_s[wrow + mt * 16 + quad * 4 + r];

    float runhp[4][4], runhn[4][4];
    #pragma unroll
    for (int mt = 0; mt < 4; ++mt)
        #pragma unroll
        for (int r = 0; r < 4; ++r) { runhp[mt][r] = -BIGF; runhn[mt][r] = BIGF; }

    const int cps = N / NSPLIT;                 // 1024
    const int cbegin = blockIdx.y * cps;

    auto bload = [&](int cb, int s0, bf16x8* dst) {
        #pragma unroll
        for (int h = 0; h < 8; ++h) {
            int s = s0 + (h >> 2), nt = h & 3;
            dst[h] = *(const bf16x8*)(xb + (size_t)(cb + wcol + nt * 16 + m16) * DK
                                      + s * 32 + quad * 8);
        }
    };

    // pipeline prologue: first tile's s=0..1 B-frags + column attrs
    bf16x8 pre01[8]; float psq[4]; int plb[4];
    bload(cbegin, 0, pre01);
    #pragma unroll
    for (int nt = 0; nt < 4; ++nt) {
        int c = cbegin + wcol + nt * 16 + m16;
        psq[nt] = sq[c]; plb[nt] = lab[c];
    }

    #pragma unroll 2
    for (int ci = 0; ci < cps; ci += 128) {
        const int cbase = cbegin + ci;

        bf16x8 c01[8]; float csq[4]; int clb[4];
        #pragma unroll
        for (int h = 0; h < 8; ++h) c01[h] = pre01[h];
        #pragma unroll
        for (int nt = 0; nt < 4; ++nt) { csq[nt] = psq[nt]; clb[nt] = plb[nt]; }

        bf16x8 c23[8];
        bload(cbase, 2, c23);                  // current tile's s=2..3

        const int nb = (ci + 128 < cps) ? (cbase + 128) : cbegin;
        bload(nb, 0, pre01);                   // NEXT tile's s=0..1 (prefetch)
        #pragma unroll
        for (int nt = 0; nt < 4; ++nt) {
            int c = nb + wcol + nt * 16 + m16;
            psq[nt] = sq[c]; plb[nt] = lab[c];
        }

        f32x4 acc[4][4];
        #pragma unroll
        for (int mt = 0; mt < 4; ++mt)
            #pragma unroll
            for (int nt = 0; nt < 4; ++nt)
                acc[mt][nt] = (f32x4){0.f, 0.f, 0.f, 0.f};

        #pragma unroll
        for (int s = 0; s < 2; ++s) {
            bf16x8 afr[4];
            #pragma unroll
            for (int mt = 0; mt < 4; ++mt)
                afr[mt] = *(const bf16x8*)(a_s + (wrow + mt * 16 + m16) * LDA
                                           + s * 32 + quad * 8);
            #pragma unroll
            for (int mt = 0; mt < 4; ++mt)
                #pragma unroll
                for (int nt = 0; nt < 4; ++nt)
                    acc[mt][nt] = __builtin_amdgcn_mfma_f32_16x16x32_bf16(
                        afr[mt], c01[s * 4 + nt], acc[mt][nt], 0, 0, 0);
        }
        #pragma unroll
        for (int s = 2; s < 4; ++s) {
            bf16x8 afr[4];
            #pragma unroll
            for (int mt = 0; mt < 4; ++mt)
                afr[mt] = *(const bf16x8*)(a_s + (wrow + mt * 16 + m16) * LDA
                                           + s * 32 + quad * 8);
            #pragma unroll
            for (int mt = 0; mt < 4; ++mt)
                #pragma unroll
                for (int nt = 0; nt < 4; ++nt)
                    acc[mt][nt] = __builtin_amdgcn_mfma_f32_16x16x32_bf16(
                        afr[mt], c23[(s - 2) * 4 + nt], acc[mt][nt], 0, 0, 0);
        }

        if (cbase == rbase) {
            // diagonal tile (wave-uniform branch): exclude self-pairs from hp
            #pragma unroll
            for (int nt = 0; nt < 4; ++nt) {
                int colg = cbase + wcol + nt * 16 + m16;
                #pragma unroll
                for (int mt = 0; mt < 4; ++mt)
                    #pragma unroll
                    for (int r = 0; r < 4; ++r) {
                        float t = fmaf(-2.0f, acc[mt][nt][r], csq[nt]);
                        int rowg = rbase + wrow + mt * 16 + quad * 4 + r;
                        bool same = (rlab[mt][r] == clb[nt]);
                        bool pos = same && (rowg != colg);
                        runhp[mt][r] = fmaxf(runhp[mt][r], pos ? t : -BIGF);
                        runhn[mt][r] = fminf(runhn[mt][r], same ? BIGF : t);
                    }
            }
        } else {
            #pragma unroll
            for (int nt = 0; nt < 4; ++nt) {
                #pragma unroll
                for (int mt = 0; mt < 4; ++mt)
                    #pragma unroll
                    for (int r = 0; r < 4; ++r) {
                        float t = fmaf(-2.0f, acc[mt][nt][r], csq[nt]);
                        bool same = (rlab[mt][r] == clb[nt]);
                        runhp[mt][r] = fmaxf(runhp[mt][r], same ? t : -BIGF);
                        runhn[mt][r] = fminf(runhn[mt][r], same ? BIGF : t);
                    }
            }
        }
    }

    // reduce across the 16 m16-lanes sharing each row
    #pragma unroll
    for (int mt = 0; mt < 4; ++mt)
        #pragma unroll
        for (int r = 0; r < 4; ++r) {
            #pragma unroll
            for (int o = 8; o > 0; o >>= 1) {
                runhp[mt][r] = fmaxf(runhp[mt][r], __shfl_xor(runhp[mt][r], o, 16));
                runhn[mt][r] = fminf(runhn[mt][r], __shfl_xor(runhn[mt][r], o, 16));
            }
        }

    if (m16 == 0) {
        #pragma unroll
        for (int mt = 0; mt < 4; ++mt)
            #pragma unroll
            for (int r = 0; r < 4; ++r) {
                int rowl = wrow + mt * 16 + quad * 4 + r;
                red_hp[rowl][wave & 1] = runhp[mt][r];
                red_hn[rowl][wave & 1] = runhn[mt][r];
            }
    }
    __syncthreads();
    if (tid < 128) {
        float thp = fmaxf(red_hp[tid][0], red_hp[tid][1]);
        float thn = fminf(red_hn[tid][0], red_hn[tid][1]);
        float sqa = sq[rbase + tid];
        // store UNclamped d2 via order-preserving keys: -BIGF/+BIGF sentinels
        // propagate "no positive/negative in this split" exactly.
        atomicMax(&hp_bits[rbase + tid], encf(sqa + thp));
        atomicMax(&hn_bits[rbase + tid], ~encf(sqa + thn));
    }

    // ---- last block does the finalize (saves a dispatch) ----
    __syncthreads();          // drains the atomics (vmcnt(0) before barrier)
    __threadfence();
    if (tid == 0) {
        unsigned tot = gridDim.x * gridDim.y;
        unsigned o = atomicAdd(bcnt, 1u);
        s_last = (o == tot - 1);
    }
    __syncthreads();
    if (!s_last) return;

    float lsum = 0.0f, lcnt = 0.0f;
    for (int base = 0; base < N; base += 256 * 8) {
        unsigned kp[8], kn[8];
        #pragma unroll
        for (int j = 0; j < 8; ++j) {
            int r = base + j * 256 + tid;
            kp[j] = (r < N) ? __hip_atomic_load(&hp_bits[r], __ATOMIC_RELAXED,
                                                __HIP_MEMORY_SCOPE_AGENT) : 0u;
            kn[j] = (r < N) ? __hip_atomic_load(&hn_bits[r], __ATOMIC_RELAXED,
                                                __HIP_MEMORY_SCOPE_AGENT) : 0u;
        }
        #pragma unroll
        for (int j = 0; j < 8; ++j) {
            int r = base + j * 256 + tid;
            if (r >= N) continue;
            float hpv = decf(kp[j]);
            float hnv = decf(~kn[j]);
            if (hpv > -0.5f * BIGF && hnv < 0.5f * BIGF) {
                float dp = sqrtf(fmaxf(hpv, 0.0f));
                float dn = sqrtf(fmaxf(hnv, 0.0f));
                lsum += fmaxf(dp - dn + MARGIN, 0.0f);
                lcnt += 1.0f;
            }
        }
    }
    s_sum[tid] = lsum; s_cnt[tid] = lcnt;
    __syncthreads();
    for (int o = 128; o > 0; o >>= 1) {
        if (tid < o) { s_sum[tid] += s_sum[tid + o]; s_cnt[tid] += s_cnt[tid + o]; }
        __syncthreads();
    }
    if (tid == 0) out[0] = (s_cnt[0] > 0.0f) ? s_sum[0] / s_cnt[0] : 0.0f;
}

extern "C" void kernel_launch(void* const* d_in, const int* in_sizes, int n_in,
                              void* d_out, int out_size, void* d_ws, size_t ws_size,
                              hipStream_t stream) {
    const float* x = (const float*)d_in[0];
    const int* lab = (const int*)d_in[1];
    float* out = (float*)d_out;
    const int N = in_sizes[1];          // 8192

    unsigned* ws = (unsigned*)d_ws;
    unsigned* hp_bits = ws + WS_HP;
    unsigned* hn_bits = ws + WS_HN;
    unsigned* bcnt    = ws + WS_BCNT;
    float* sq  = (float*)(ws + WS_SQ);
    ushort* xb = (ushort*)(ws + WS_XB);

    prep_kernel<<<N / 4, 256, 0, stream>>>(x, xb, sq, hp_bits, hn_bits, bcnt, N);
    dim3 grid(N / 128, NSPLIT);
    tile_kernel<<<grid, 256, 0, stream>>>(xb, sq, lab, hp_bits, hn_bits, bcnt, out, N);
}